// Round 5
// baseline (3044.272 us; speedup 1.0000x reference)
//
#include <hip/hip_runtime.h>
#include <stdint.h>

#define B_    128
#define F_    4
#define V_    2048
#define D_    4096
#define DW    64      // D/64 bit-words per (b,f) row
#define VW    32      // V/64 bit-words per d column
#define ITERS 20
#define NKT   16      // K tiles of 128 over V=2048
#define NBLK  512

typedef _Float16 half8 __attribute__((ext_vector_type(8)));
typedef float   floatx4 __attribute__((ext_vector_type(4)));

// Pack 16 floats (+-1.0 exactly) -> 16 sign bits -> 2-byte store into bitstream.
__device__ __forceinline__ void pack16(const float* __restrict__ x,
                                       uint64_t* __restrict__ bits, int t) {
    const float4* p = (const float4*)x + (size_t)t * 4;
    uint32_t m = 0;
    #pragma unroll
    for (int j = 0; j < 4; ++j) {
        float4 v = p[j];
        m |= (__float_as_uint(v.x) >> 31) << (4 * j + 0);
        m |= (__float_as_uint(v.y) >> 31) << (4 * j + 1);
        m |= (__float_as_uint(v.z) >> 31) << (4 * j + 2);
        m |= (__float_as_uint(v.w) >> 31) << (4 * j + 3);
    }
    ((unsigned short*)bits)[t] = (unsigned short)m;
}

// Hand-rolled grid barrier: count + generation, device-scope atomics.
// Co-residency by construction: launch_bounds(256,2) forces VGPR<=256
// (2 waves/EU), 48KB LDS -> 2 blocks/CU x 256 CU = 512 = NBLK.
// Bounded spin (~28 ms) converts a co-residency failure into a wrong
// answer instead of a container-killing hang.
__device__ __forceinline__ void grid_sync(int* bar, int target) {
    __syncthreads();
    if (threadIdx.x == 0) {
        __threadfence();                                   // agent release (L2 wb)
        if (atomicAdd(&bar[0], 1) == NBLK - 1) {
            atomicExch(&bar[0], 0);                        // reset count
            __threadfence();                               // order reset before gen bump
            atomicAdd(&bar[1], 1);                         // open generation
        } else {
            int spins = 0;
            while (__hip_atomic_load(&bar[1], __ATOMIC_RELAXED,
                                     __HIP_MEMORY_SCOPE_AGENT) < target) {
                __builtin_amdgcn_s_sleep(8);
                if (++spins > (1 << 17)) break;            // bailout: fail, don't hang
            }
        }
        __threadfence();                                   // agent acquire (L2 inv)
    }
    __syncthreads();
}

// ------------------------------------------------------------------
// ONE persistent kernel (plain launch, graph-capturable):
// pack -> packT -> 20x(sim -> gemm) -> argmax -> final.
// No early break: the step is a deterministic fixed-point map, so
// running all 20 iterations is output-identical (flags still record
// per-iteration change for k). This removes the only construct that
// could make blocks disagree on barrier counts (R4 hang suspect).
// 512 blocks x 256 thr, 48 KB LDS. Algorithms byte-identical to the
// verified round-2 split kernels.
// ------------------------------------------------------------------
__global__ __launch_bounds__(256, 2) void k_fused(
        const float* __restrict__ cb, const float* __restrict__ inite,
        const float* __restrict__ inputs,
        uint64_t* __restrict__ cb_bits, uint64_t* __restrict__ cbT,
        uint64_t* __restrict__ est_bits, uint64_t* __restrict__ in_bits,
        _Float16* __restrict__ simf, int* __restrict__ flags,
        int* __restrict__ keys, int* __restrict__ out, int* bar) {
    const int bid = blockIdx.x;
    const int tid = threadIdx.x;
    const int gtid = bid * 256 + tid;              // 0 .. 131071
    const int T = NBLK * 256;
    int ng = 0;                                    // barrier generation (uniform)

    __shared__ __align__(16) unsigned char LDSU[49152];   // 48 KB, re-used per phase
    __shared__ int bd;

    // ============ phase A: bit-pack inputs, zero flags/keys ============
    {
        const int ncb = (F_ * V_ * D_) / 16;       // 2097152 -> 16 per thread
        for (int t = gtid; t < ncb; t += T) pack16(cb, cb_bits, t);
        pack16(inite, est_bits, gtid);             // exactly 131072 tasks
        if (gtid < (B_ * D_) / 16) pack16(inputs, in_bits, gtid);
        if (gtid < 32) flags[gtid] = 0;
        if (gtid < B_ * F_) keys[gtid] = 0;
    }
    grid_sync(bar, ++ng);

    // ============ phase B: transpose cb bits -> cbT ====================
    {
        int wave = tid >> 6, lane = tid & 63;
        #pragma unroll 1
        for (int s = 0; s < 4; ++s) {
            int u = (bid * 4 + wave) + 2048 * s;   // 8192 (vw,dw,f) units
            int vw = u & 31, dw = (u >> 5) & 63, f = u >> 11;
            uint64_t w = cb_bits[((size_t)f * V_ + vw * 64 + lane) * DW + dw];
            uint64_t r = 0;
            for (int d2 = 0; d2 < 64; ++d2) {
                uint64_t m = __ballot((unsigned)((w >> d2) & 1));
                if (lane == d2) r = m;
            }
            cbT[((size_t)f * D_ + dw * 64 + lane) * VW + vw] = r;
        }
    }
    grid_sync(bar, ++ng);

    // ============ iteration loop (always 20; fixed-point => identical) =
    #pragma unroll 1
    for (int i = 0; i < ITERS; ++i) {
        // ---- sim: LDS-tiled bit-GEMM, tile 64v x 32b per block ----
        {
            int vt = bid & 31, bt = (bid >> 5) & 3, f = bid >> 7;
            int v0 = vt * 64, b0 = bt * 32;
            ulonglong2* CB2 = (ulonglong2*)LDSU;            // 64*32 chunks, 32 KB
            ulonglong2* NB2 = (ulonglong2*)(LDSU + 32768);  // 32*32 chunks, 16 KB
            #pragma unroll
            for (int it = 0; it < 8; ++it) {
                int cq = it * 256 + tid;                    // 2048 chunks
                int r = cq >> 5, ch = cq & 31;
                const ulonglong2* src = (const ulonglong2*)(cb_bits + ((size_t)f * V_ + v0 + r) * DW);
                CB2[r * 32 + (ch ^ (r & 7))] = src[ch];
            }
            #pragma unroll
            for (int it = 0; it < 4; ++it) {
                int cq = it * 256 + tid;                    // 1024 chunks
                int r = cq >> 5, ch = cq & 31;
                int b = b0 + r;
                const ulonglong2* iv = (const ulonglong2*)(in_bits + (size_t)b * DW);
                const uint64_t* eb = est_bits + (size_t)b * F_ * DW;
                ulonglong2 i2 = iv[ch];
                ulonglong2 e0 = ((const ulonglong2*)(eb + 0 * DW))[ch];
                ulonglong2 e1 = ((const ulonglong2*)(eb + 1 * DW))[ch];
                ulonglong2 e2 = ((const ulonglong2*)(eb + 2 * DW))[ch];
                ulonglong2 e3 = ((const ulonglong2*)(eb + 3 * DW))[ch];
                ulonglong2 es = ((const ulonglong2*)(eb + (size_t)f * DW))[ch];
                ulonglong2 val;
                val.x = i2.x ^ e0.x ^ e1.x ^ e2.x ^ e3.x ^ es.x;
                val.y = i2.y ^ e0.y ^ e1.y ^ e2.y ^ e3.y ^ es.y;
                NB2[r * 32 + (ch ^ (r & 7))] = val;
            }
            __syncthreads();

            int vv = tid & 15, bb = tid >> 4;
            int svz = vv & 7, sbz = bb & 7;
            int pc[2][4];
            #pragma unroll
            for (int j = 0; j < 2; ++j)
                #pragma unroll
                for (int ii = 0; ii < 4; ++ii) pc[j][ii] = 0;

            #pragma unroll 4
            for (int ch = 0; ch < 32; ++ch) {
                ulonglong2 c[4], n[2];
                #pragma unroll
                for (int ii = 0; ii < 4; ++ii)
                    c[ii] = CB2[(vv + 16 * ii) * 32 + (ch ^ svz)];
                #pragma unroll
                for (int j = 0; j < 2; ++j)
                    n[j] = NB2[(bb + 16 * j) * 32 + (ch ^ sbz)];
                #pragma unroll
                for (int j = 0; j < 2; ++j)
                    #pragma unroll
                    for (int ii = 0; ii < 4; ++ii)
                        pc[j][ii] += __popcll(n[j].x ^ c[ii].x) + __popcll(n[j].y ^ c[ii].y);
            }
            #pragma unroll
            for (int j = 0; j < 2; ++j) {
                int b = b0 + bb + 16 * j;
                #pragma unroll
                for (int ii = 0; ii < 4; ++ii) {
                    int v = v0 + vv + 16 * ii;
                    simf[((size_t)f * B_ + b) * V_ + v] = (_Float16)(2048 - pc[j][ii]);
                }
            }
        }
        grid_sync(bar, ++ng);

        // ---- gemm: C[b,d] = sum_v sim * (+-1), hardsign -> est_bits ----
        {
            int gnt = bid & 63, gmt = (bid >> 6) & 1, gf = bid >> 7;
            int m0 = gmt * 64, n0 = gnt * 64;
            int lane = tid & 63, wave = tid >> 6;
            int lrow = lane & 15, lq = lane >> 4;
            int wm = wave & 1, wn = wave >> 1;

            uint64_t* Bb = (uint64_t*)LDSU;                 // 16 KB, swizzled chunks
            _Float16* As = (_Float16*)(LDSU + 16384);       // 16 KB, swizzled chunks
            if (tid == 0) bd = 0;

            const uint64_t* bsrc = cbT + ((size_t)gf * D_ + n0) * VW;
            #pragma unroll
            for (int p = 0; p < 4; ++p) {
                int chunk = p * 256 + tid;                  // 1024 chunks
                int dloc = chunk >> 4, cw = chunk & 15;
                ulonglong2 val = *(const ulonglong2*)&bsrc[dloc * VW + cw * 2];
                *(ulonglong2*)&Bb[dloc * VW + ((cw ^ (dloc & 15)) * 2)] = val;
            }

            const _Float16* Ab = simf + (size_t)gf * B_ * V_ + (size_t)m0 * V_;
            int arow = tid >> 4, acol = tid & 15;
            half8 areg[4];
            #pragma unroll
            for (int p = 0; p < 4; ++p)
                areg[p] = *(const half8*)&Ab[(size_t)(p * 16 + arow) * V_ + acol * 8];

            floatx4 acc[2][2] = {};

            const uint64_t SPREAD = 0x1000200040008000ull;  // bit b -> pos 15+16b
            const uint64_t SMASK  = 0x8000800080008000ull;
            const uint64_t PONE   = 0x3C003C003C003C00ull;  // f16 +1.0 x4

            #pragma unroll 1
            for (int kt = 0; kt < NKT; ++kt) {
                __syncthreads();
                #pragma unroll
                for (int p = 0; p < 4; ++p)
                    *(half8*)&As[(p * 16 + arow) * 128 + ((acol ^ arow) * 8)] = areg[p];
                if (kt + 1 < NKT) {
                    #pragma unroll
                    for (int p = 0; p < 4; ++p)
                        areg[p] = *(const half8*)&Ab[(size_t)(p * 16 + arow) * V_ + (kt + 1) * 128 + acol * 8];
                }
                __syncthreads();

                ulonglong2 bw[2];
                #pragma unroll
                for (int nt2 = 0; nt2 < 2; ++nt2) {
                    int dloc = wn * 32 + nt2 * 16 + lrow;
                    bw[nt2] = *(const ulonglong2*)&Bb[dloc * VW + ((kt ^ (dloc & 15)) * 2)];
                }
                #pragma unroll
                for (int ks = 0; ks < 4; ++ks) {
                    half8 af[2];
                    #pragma unroll
                    for (int mt2 = 0; mt2 < 2; ++mt2) {
                        int row = wm * 32 + mt2 * 16 + lrow;
                        af[mt2] = *(const half8*)&As[row * 128 + (((ks * 4 + lq) ^ lrow) * 8)];
                    }
                    half8 bfrag[2];
                    #pragma unroll
                    for (int nt2 = 0; nt2 < 2; ++nt2) {
                        uint64_t w = (ks < 2) ? bw[nt2].x : bw[nt2].y;
                        uint32_t byte = (uint32_t)(w >> ((((ks & 1) * 4 + lq)) * 8)) & 0xFFu;
                        union { uint64_t q[2]; half8 h; } bu;
                        bu.q[0] = (((uint64_t)(byte & 0xFu) * SPREAD) & SMASK) ^ PONE;
                        bu.q[1] = (((uint64_t)(byte >> 4)   * SPREAD) & SMASK) ^ PONE;
                        bfrag[nt2] = bu.h;
                    }
                    #pragma unroll
                    for (int mt2 = 0; mt2 < 2; ++mt2)
                        #pragma unroll
                        for (int nt2 = 0; nt2 < 2; ++nt2)
                            acc[mt2][nt2] = __builtin_amdgcn_mfma_f32_16x16x32_f16(
                                af[mt2], bfrag[nt2], acc[mt2][nt2], 0, 0, 0);
                }
            }

            // epilogue: hardsign -> LDS bytes -> bit-pack u64 per row
            __syncthreads();
            unsigned char* S = (unsigned char*)As;
            #pragma unroll
            for (int mt2 = 0; mt2 < 2; ++mt2)
                #pragma unroll
                for (int nt2 = 0; nt2 < 2; ++nt2)
                    #pragma unroll
                    for (int r = 0; r < 4; ++r) {
                        int row = wm * 32 + mt2 * 16 + lq * 4 + r;   // C/D: row = quad*4+reg
                        int col = wn * 32 + nt2 * 16 + lrow;         // col = lane&15
                        S[row * 64 + col] = (acc[mt2][nt2][r] < 0.0f) ? 1 : 0;  // sign(0)=+1
                    }
            __syncthreads();
            if (tid < 64) {
                const uint64_t* Sw = (const uint64_t*)S;
                uint64_t m = 0;
                #pragma unroll
                for (int j = 0; j < 8; ++j) {
                    uint64_t w = Sw[tid * 8 + j];
                    m |= ((w * 0x0102040810204080ull) >> 56) << (8 * j);
                }
                size_t widx = ((size_t)(m0 + tid) * F_ + gf) * DW + gnt;
                uint64_t old = est_bits[widx];
                est_bits[widx] = m;
                if (old != m) atomicOr(&bd, 1);
            }
            __syncthreads();
            if (tid == 0 && bd) atomicOr(&flags[i], 1);
        }
        grid_sync(bar, ++ng);
    }

    // ============ argmax phase: tile 32v x 64b per block ===============
    {
        int vt = bid & 63, bg = (bid >> 6) & 1, f = bid >> 7;
        int v0 = vt * 32, b0g = bg * 64;
        ulonglong2* EB2 = (ulonglong2*)LDSU;            // 64*32 chunks, 32 KB
        ulonglong2* CBa = (ulonglong2*)(LDSU + 32768);  // 32*32 chunks, 16 KB
        #pragma unroll
        for (int it = 0; it < 8; ++it) {
            int cq = it * 256 + tid;                    // 2048 chunks
            int r = cq >> 5, ch = cq & 31;
            const ulonglong2* src = (const ulonglong2*)(est_bits + ((size_t)(b0g + r) * F_ + f) * DW);
            EB2[r * 32 + (ch ^ (r & 7))] = src[ch];
        }
        #pragma unroll
        for (int it = 0; it < 4; ++it) {
            int cq = it * 256 + tid;                    // 1024 chunks
            int r = cq >> 5, ch = cq & 31;
            const ulonglong2* src = (const ulonglong2*)(cb_bits + ((size_t)f * V_ + v0 + r) * DW);
            CBa[r * 32 + (ch ^ (r & 7))] = src[ch];
        }
        __syncthreads();

        int vv = tid & 15, bb = tid >> 4;
        int svz = vv & 7, sbz = bb & 7;
        int pc[4][2];
        #pragma unroll
        for (int j = 0; j < 4; ++j) { pc[j][0] = 0; pc[j][1] = 0; }

        #pragma unroll 4
        for (int ch = 0; ch < 32; ++ch) {
            ulonglong2 c[2], n[4];
            #pragma unroll
            for (int ii = 0; ii < 2; ++ii)
                c[ii] = CBa[(vv + 16 * ii) * 32 + (ch ^ svz)];
            #pragma unroll
            for (int j = 0; j < 4; ++j)
                n[j] = EB2[(bb + 16 * j) * 32 + (ch ^ sbz)];
            #pragma unroll
            for (int j = 0; j < 4; ++j)
                #pragma unroll
                for (int ii = 0; ii < 2; ++ii)
                    pc[j][ii] += __popcll(n[j].x ^ c[ii].x) + __popcll(n[j].y ^ c[ii].y);
        }
        #pragma unroll
        for (int j = 0; j < 4; ++j) {
            int kj = (int)0x80000000;
            #pragma unroll
            for (int ii = 0; ii < 2; ++ii) {
                int v = v0 + vv + 16 * ii;
                int m = 2048 - pc[j][ii]; if (m < 0) m = -m;
                int key = (m << 11) | (2047 - v);
                if (key > kj) kj = key;
            }
            #pragma unroll
            for (int s = 1; s < 16; s <<= 1) {
                int o = __shfl_xor(kj, s, 64);
                if (o > kj) kj = o;
            }
            if ((tid & 15) == 0)
                atomicMax(&keys[(size_t)(b0g + bb + 16 * j) * F_ + f], kj);
        }
    }
    grid_sync(bar, ++ng);

    // ============ final outputs =======================================
    if (bid == 0) {
        for (int t = tid; t < B_ * F_; t += 256)
            out[t] = 2047 - (keys[t] & 0x7FF);
        if (tid == 0) {
            int k = ITERS - 1;
            for (int i2 = 0; i2 < ITERS; ++i2) {
                int fl = __hip_atomic_load(&flags[i2], __ATOMIC_RELAXED,
                                           __HIP_MEMORY_SCOPE_AGENT);
                if (fl == 0) { k = i2; break; }
            }
            out[B_ * F_] = k;
        }
    }
}

// ------------------------------------------------------------------
extern "C" void kernel_launch(void* const* d_in, const int* in_sizes, int n_in,
                              void* d_out, int out_size, void* d_ws, size_t ws_size,
                              hipStream_t stream) {
    const float* inputs = (const float*)d_in[0];   // (B, D)
    const float* inite  = (const float*)d_in[1];   // (B, F, D)
    const float* cb     = (const float*)d_in[2];   // (F, V, D)
    int* out = (int*)d_out;                        // 512 outcome + 1 k

    char* ws = (char*)d_ws;
    uint64_t* cb_bits  = (uint64_t*)ws;  ws += (size_t)F_ * V_ * DW * 8;   // 4 MiB
    uint64_t* cbT_bits = (uint64_t*)ws;  ws += (size_t)F_ * D_ * VW * 8;   // 4 MiB
    uint64_t* est_bits = (uint64_t*)ws;  ws += (size_t)B_ * F_ * DW * 8;   // 256 KiB
    uint64_t* in_bits  = (uint64_t*)ws;  ws += (size_t)B_ * DW * 8;        // 64 KiB
    _Float16* simf     = (_Float16*)ws;  ws += (size_t)F_ * B_ * V_ * 2;   // 2 MiB
    int*      flags    = (int*)ws;       ws += 32 * 4;
    int*      keys     = (int*)ws;       ws += B_ * F_ * 4;
    int*      bar      = (int*)ws;       ws += 64;

    // bar must be zero at kernel start on EVERY graph replay: the memset
    // is part of the captured stream, so it re-executes each replay.
    hipMemsetAsync(bar, 0, 64, stream);

    k_fused<<<dim3(NBLK), dim3(256), 0, stream>>>(
        cb, inite, inputs, cb_bits, cbT_bits, est_bits, in_bits,
        simf, flags, keys, out, bar);
}

// Round 6
// 950.388 us; speedup vs baseline: 3.2032x; 3.2032x over previous
//
#include <hip/hip_runtime.h>
#include <stdint.h>

#define B_    128
#define F_    4
#define V_    2048
#define D_    4096
#define DW    64      // D/64 bit-words per (b,f) row
#define VW    32      // V/64 bit-words per d column
#define ITERS 20
#define NKT   16      // K tiles of 128 over V=2048

typedef _Float16 half8 __attribute__((ext_vector_type(8)));
typedef float   floatx4 __attribute__((ext_vector_type(4)));

__device__ __forceinline__ void pack16(const float* __restrict__ x,
                                       uint64_t* __restrict__ bits, int t) {
    const float4* p = (const float4*)x + (size_t)t * 4;
    uint32_t m = 0;
    #pragma unroll
    for (int j = 0; j < 4; ++j) {
        float4 v = p[j];
        m |= (__float_as_uint(v.x) >> 31) << (4 * j + 0);
        m |= (__float_as_uint(v.y) >> 31) << (4 * j + 1);
        m |= (__float_as_uint(v.z) >> 31) << (4 * j + 2);
        m |= (__float_as_uint(v.w) >> 31) << (4 * j + 3);
    }
    ((unsigned short*)bits)[t] = (unsigned short)m;
}

// ------------------------------------------------------------------
// Setup: all three bit-packs + flag/key zeroing in ONE dispatch.
// grid 512 x 256 = 131072 threads; cb loops 16x, others 1x.
// ------------------------------------------------------------------
__global__ __launch_bounds__(256) void k_setup(
        const float* __restrict__ cb, const float* __restrict__ inite,
        const float* __restrict__ inputs,
        uint64_t* __restrict__ cb_bits, uint64_t* __restrict__ est_bits,
        uint64_t* __restrict__ in_bits,
        int* __restrict__ flags, int* __restrict__ keys) {
    int gtid = blockIdx.x * 256 + threadIdx.x;     // 0..131071
    const int T = 512 * 256;
    const int ncb = (F_ * V_ * D_) / 16;           // 2097152
    for (int t = gtid; t < ncb; t += T) pack16(cb, cb_bits, t);
    pack16(inite, est_bits, gtid);                 // exactly 131072
    if (gtid < (B_ * D_) / 16) pack16(inputs, in_bits, gtid);
    if (gtid < 32) flags[gtid] = 0;
    if (gtid < B_ * F_) keys[gtid] = 0;
}

// ------------------------------------------------------------------
// Transpose cb_bits[f][v][dwords] -> cbT[f][d][vwords] (bit v of word).
// ------------------------------------------------------------------
__global__ void k_packT(const uint64_t* __restrict__ cb_bits,
                        uint64_t* __restrict__ cbT) {
    int vw = blockIdx.x, dwg = blockIdx.y, f = blockIdx.z;
    int lane = threadIdx.x & 63;
    int dw = dwg * 4 + (threadIdx.x >> 6);
    uint64_t w = cb_bits[((size_t)f * V_ + vw * 64 + lane) * DW + dw];
    uint64_t r = 0;
    for (int d2 = 0; d2 < 64; ++d2) {
        uint64_t m = __ballot((unsigned)((w >> d2) & 1));
        if (lane == d2) r = m;
    }
    cbT[((size_t)f * D_ + dw * 64 + lane) * VW + vw] = r;
}

// ------------------------------------------------------------------
// sim[b,f,v] = 2048 - popcount(new_est ^ cb_row), exact fp16.
// LDS bit-GEMM, tile 64v x 32b, 48 KB LDS, grid (32,4,4)=512 blocks
// -> 2 blocks/CU, 8 waves/CU (R2 ran 1 block/CU = 1 wave/SIMD).
// Phase code correctness-validated in R5's fused kernel (absmax 0).
// ------------------------------------------------------------------
__global__ __launch_bounds__(256) void k_sim(
        const uint64_t* __restrict__ cb_bits,
        const uint64_t* __restrict__ in_bits,
        const uint64_t* __restrict__ est_bits,
        _Float16* __restrict__ simf,
        const int* __restrict__ flags, int iter) {
    if (iter > 0 && flags[iter - 1] == 0) return;
    int vt = blockIdx.x, bt = blockIdx.y, f = blockIdx.z;
    int v0 = vt * 64, b0 = bt * 32;
    int tid = threadIdx.x;

    __shared__ __align__(16) ulonglong2 CB2[64 * 32];   // 32 KB
    __shared__ __align__(16) ulonglong2 NB2[32 * 32];   // 16 KB

    #pragma unroll
    for (int it = 0; it < 8; ++it) {
        int cq = it * 256 + tid;                    // 2048 chunks
        int r = cq >> 5, ch = cq & 31;
        const ulonglong2* src = (const ulonglong2*)(cb_bits + ((size_t)f * V_ + v0 + r) * DW);
        CB2[r * 32 + (ch ^ (r & 7))] = src[ch];
    }
    #pragma unroll
    for (int it = 0; it < 4; ++it) {
        int cq = it * 256 + tid;                    // 1024 chunks
        int r = cq >> 5, ch = cq & 31;
        int b = b0 + r;
        const ulonglong2* iv = (const ulonglong2*)(in_bits + (size_t)b * DW);
        const uint64_t* eb = est_bits + (size_t)b * F_ * DW;
        ulonglong2 i2 = iv[ch];
        ulonglong2 e0 = ((const ulonglong2*)(eb + 0 * DW))[ch];
        ulonglong2 e1 = ((const ulonglong2*)(eb + 1 * DW))[ch];
        ulonglong2 e2 = ((const ulonglong2*)(eb + 2 * DW))[ch];
        ulonglong2 e3 = ((const ulonglong2*)(eb + 3 * DW))[ch];
        ulonglong2 es = ((const ulonglong2*)(eb + (size_t)f * DW))[ch];
        ulonglong2 val;
        val.x = i2.x ^ e0.x ^ e1.x ^ e2.x ^ e3.x ^ es.x;
        val.y = i2.y ^ e0.y ^ e1.y ^ e2.y ^ e3.y ^ es.y;
        NB2[r * 32 + (ch ^ (r & 7))] = val;
    }
    __syncthreads();

    int vv = tid & 15, bb = tid >> 4;
    int svz = vv & 7, sbz = bb & 7;
    int pc[2][4];
    #pragma unroll
    for (int j = 0; j < 2; ++j)
        #pragma unroll
        for (int i = 0; i < 4; ++i) pc[j][i] = 0;

    #pragma unroll 4
    for (int ch = 0; ch < 32; ++ch) {
        ulonglong2 c[4], n[2];
        #pragma unroll
        for (int i = 0; i < 4; ++i)
            c[i] = CB2[(vv + 16 * i) * 32 + (ch ^ svz)];
        #pragma unroll
        for (int j = 0; j < 2; ++j)
            n[j] = NB2[(bb + 16 * j) * 32 + (ch ^ sbz)];
        #pragma unroll
        for (int j = 0; j < 2; ++j)
            #pragma unroll
            for (int i = 0; i < 4; ++i)
                pc[j][i] += __popcll(n[j].x ^ c[i].x) + __popcll(n[j].y ^ c[i].y);
    }
    #pragma unroll
    for (int j = 0; j < 2; ++j) {
        int b = b0 + bb + 16 * j;
        #pragma unroll
        for (int i = 0; i < 4; ++i) {
            int v = v0 + vv + 16 * i;
            simf[((size_t)f * B_ + b) * V_ + v] = (_Float16)(2048 - pc[j][i]);
        }
    }
}

// ------------------------------------------------------------------
// C[b,d] = sum_v sim[b,v] * (+-1 from cbT bits); hardsign -> est_bits.
// BM=64 BN=64 BK=128; grid (nt=64, mt=2, f=4)=512 blocks, 256 thr.
// Byte-identical to the R2-verified kernel.
// ------------------------------------------------------------------
__global__ __launch_bounds__(256) void k_gemm(
        const _Float16* __restrict__ simf,
        const uint64_t* __restrict__ cbT,
        uint64_t* __restrict__ est_bits,
        int* __restrict__ flags, int iter) {
    if (iter > 0 && flags[iter - 1] == 0) return;
    int nt = blockIdx.x, mt = blockIdx.y, f = blockIdx.z;
    int m0 = mt * 64, n0 = nt * 64;
    int tid = threadIdx.x;
    int lane = tid & 63, wave = tid >> 6;
    int lrow = lane & 15, lq = lane >> 4;
    int wm = wave & 1, wn = wave >> 1;

    __shared__ __align__(16) uint64_t Bb[64 * VW];      // 16 KB, swizzled chunks
    __shared__ __align__(16) _Float16 As[64 * 128];     // 16 KB, swizzled chunks
    __shared__ int bd;
    if (tid == 0) bd = 0;

    const uint64_t* bsrc = cbT + ((size_t)f * D_ + n0) * VW;
    #pragma unroll
    for (int p = 0; p < 4; ++p) {
        int chunk = p * 256 + tid;                 // 1024 chunks
        int dloc = chunk >> 4, cw = chunk & 15;
        ulonglong2 val = *(const ulonglong2*)&bsrc[dloc * VW + cw * 2];
        *(ulonglong2*)&Bb[dloc * VW + ((cw ^ (dloc & 15)) * 2)] = val;
    }

    const _Float16* Ab = simf + (size_t)f * B_ * V_ + (size_t)m0 * V_;
    int arow = tid >> 4, acol = tid & 15;
    half8 areg[4];
    #pragma unroll
    for (int p = 0; p < 4; ++p)
        areg[p] = *(const half8*)&Ab[(size_t)(p * 16 + arow) * V_ + acol * 8];

    floatx4 acc[2][2] = {};

    const uint64_t SPREAD = 0x1000200040008000ull;  // bit b -> pos 15+16b
    const uint64_t SMASK  = 0x8000800080008000ull;
    const uint64_t PONE   = 0x3C003C003C003C00ull;  // f16 +1.0 x4

    #pragma unroll 1
    for (int kt = 0; kt < NKT; ++kt) {
        __syncthreads();
        #pragma unroll
        for (int p = 0; p < 4; ++p)
            *(half8*)&As[(p * 16 + arow) * 128 + ((acol ^ arow) * 8)] = areg[p];
        if (kt + 1 < NKT) {
            #pragma unroll
            for (int p = 0; p < 4; ++p)
                areg[p] = *(const half8*)&Ab[(size_t)(p * 16 + arow) * V_ + (kt + 1) * 128 + acol * 8];
        }
        __syncthreads();

        ulonglong2 bw[2];
        #pragma unroll
        for (int nt2 = 0; nt2 < 2; ++nt2) {
            int dloc = wn * 32 + nt2 * 16 + lrow;
            bw[nt2] = *(const ulonglong2*)&Bb[dloc * VW + ((kt ^ (dloc & 15)) * 2)];
        }
        #pragma unroll
        for (int ks = 0; ks < 4; ++ks) {
            half8 af[2];
            #pragma unroll
            for (int mt2 = 0; mt2 < 2; ++mt2) {
                int row = wm * 32 + mt2 * 16 + lrow;
                af[mt2] = *(const half8*)&As[row * 128 + (((ks * 4 + lq) ^ lrow) * 8)];
            }
            half8 bfrag[2];
            #pragma unroll
            for (int nt2 = 0; nt2 < 2; ++nt2) {
                uint64_t w = (ks < 2) ? bw[nt2].x : bw[nt2].y;
                uint32_t byte = (uint32_t)(w >> ((((ks & 1) * 4 + lq)) * 8)) & 0xFFu;
                union { uint64_t q[2]; half8 h; } bu;
                bu.q[0] = (((uint64_t)(byte & 0xFu) * SPREAD) & SMASK) ^ PONE;
                bu.q[1] = (((uint64_t)(byte >> 4)   * SPREAD) & SMASK) ^ PONE;
                bfrag[nt2] = bu.h;
            }
            #pragma unroll
            for (int mt2 = 0; mt2 < 2; ++mt2)
                #pragma unroll
                for (int nt2 = 0; nt2 < 2; ++nt2)
                    acc[mt2][nt2] = __builtin_amdgcn_mfma_f32_16x16x32_f16(
                        af[mt2], bfrag[nt2], acc[mt2][nt2], 0, 0, 0);
        }
    }

    // epilogue: hardsign -> LDS bytes -> bit-pack 64-bit word per row
    __syncthreads();
    unsigned char* S = (unsigned char*)As;
    #pragma unroll
    for (int mt2 = 0; mt2 < 2; ++mt2)
        #pragma unroll
        for (int nt2 = 0; nt2 < 2; ++nt2)
            #pragma unroll
            for (int r = 0; r < 4; ++r) {
                int row = wm * 32 + mt2 * 16 + lq * 4 + r;   // C/D: row = quad*4+reg
                int col = wn * 32 + nt2 * 16 + lrow;         // col = lane&15
                S[row * 64 + col] = (acc[mt2][nt2][r] < 0.0f) ? 1 : 0;  // sign(0)=+1
            }
    __syncthreads();
    if (tid < 64) {
        const uint64_t* Sw = (const uint64_t*)S;
        uint64_t m = 0;
        #pragma unroll
        for (int j = 0; j < 8; ++j) {
            uint64_t w = Sw[tid * 8 + j];
            m |= ((w * 0x0102040810204080ull) >> 56) << (8 * j);
        }
        size_t widx = ((size_t)(m0 + tid) * F_ + f) * DW + nt;
        uint64_t old = est_bits[widx];
        est_bits[widx] = m;
        if (old != m) atomicOr(&bd, 1);
    }
    __syncthreads();
    if (tid == 0 && bd) atomicOr(&flags[iter], 1);
}

// ------------------------------------------------------------------
// argmax_v |sim|: key = (|2048-pc|<<11) | (2047-v), atomicMax.
// R2-verified. grid (vt=64, f=4) = 256 blocks, 256 thr, 80 KB LDS.
// ------------------------------------------------------------------
__global__ __launch_bounds__(256) void k_argmax(
        const uint64_t* __restrict__ cb_bits,
        const uint64_t* __restrict__ est_bits,
        int* __restrict__ keys) {
    int vt = blockIdx.x, f = blockIdx.y;
    int v0 = vt * 32;
    int tid = threadIdx.x;

    __shared__ __align__(16) ulonglong2 EB2[128 * 32];  // 64 KB
    __shared__ __align__(16) ulonglong2 CBa[32 * 32];   // 16 KB

    #pragma unroll
    for (int it = 0; it < 16; ++it) {
        int cq = it * 256 + tid;                 // 4096 chunks
        int r = cq >> 5, ch = cq & 31;
        const ulonglong2* src = (const ulonglong2*)(est_bits + ((size_t)r * F_ + f) * DW);
        EB2[r * 32 + (ch ^ (r & 7))] = src[ch];
    }
    #pragma unroll
    for (int it = 0; it < 4; ++it) {
        int cq = it * 256 + tid;                 // 1024 chunks
        int r = cq >> 5, ch = cq & 31;
        const ulonglong2* src = (const ulonglong2*)(cb_bits + ((size_t)f * V_ + v0 + r) * DW);
        CBa[r * 32 + (ch ^ (r & 7))] = src[ch];
    }
    __syncthreads();

    int vv = tid & 15, bb = tid >> 4;
    int svz = vv & 7, sbz = bb & 7;
    int pc[8][2];
    #pragma unroll
    for (int j = 0; j < 8; ++j) { pc[j][0] = 0; pc[j][1] = 0; }

    #pragma unroll 4
    for (int ch = 0; ch < 32; ++ch) {
        ulonglong2 c[2], n[8];
        #pragma unroll
        for (int i = 0; i < 2; ++i)
            c[i] = CBa[(vv + 16 * i) * 32 + (ch ^ svz)];
        #pragma unroll
        for (int j = 0; j < 8; ++j)
            n[j] = EB2[(bb + 16 * j) * 32 + (ch ^ sbz)];
        #pragma unroll
        for (int j = 0; j < 8; ++j)
            #pragma unroll
            for (int i = 0; i < 2; ++i)
                pc[j][i] += __popcll(n[j].x ^ c[i].x) + __popcll(n[j].y ^ c[i].y);
    }

    #pragma unroll
    for (int j = 0; j < 8; ++j) {
        int kj = (int)0x80000000;
        #pragma unroll
        for (int i = 0; i < 2; ++i) {
            int v = v0 + vv + 16 * i;
            int m = 2048 - pc[j][i]; if (m < 0) m = -m;
            int key = (m << 11) | (2047 - v);
            if (key > kj) kj = key;
        }
        #pragma unroll
        for (int s = 1; s < 16; s <<= 1) {
            int o = __shfl_xor(kj, s, 64);
            if (o > kj) kj = o;
        }
        if ((tid & 15) == 0)
            atomicMax(&keys[(size_t)(bb + 16 * j) * F_ + f], kj);
    }
}

__global__ void k_final(const int* __restrict__ keys, const int* __restrict__ flags,
                        int* __restrict__ out) {
    int tid = blockIdx.x * blockDim.x + threadIdx.x;
    if (tid < B_ * F_) out[tid] = 2047 - (keys[tid] & 0x7FF);
    if (tid == 0) {
        int k = ITERS - 1;
        for (int i = 0; i < ITERS; ++i) if (flags[i] == 0) { k = i; break; }
        out[B_ * F_] = k;
    }
}

// ------------------------------------------------------------------
extern "C" void kernel_launch(void* const* d_in, const int* in_sizes, int n_in,
                              void* d_out, int out_size, void* d_ws, size_t ws_size,
                              hipStream_t stream) {
    const float* inputs = (const float*)d_in[0];   // (B, D)
    const float* inite  = (const float*)d_in[1];   // (B, F, D)
    const float* cb     = (const float*)d_in[2];   // (F, V, D)
    int* out = (int*)d_out;                        // 512 outcome + 1 k

    char* ws = (char*)d_ws;
    uint64_t* cb_bits  = (uint64_t*)ws;  ws += (size_t)F_ * V_ * DW * 8;   // 4 MiB
    uint64_t* cbT_bits = (uint64_t*)ws;  ws += (size_t)F_ * D_ * VW * 8;   // 4 MiB
    uint64_t* est_bits = (uint64_t*)ws;  ws += (size_t)B_ * F_ * DW * 8;   // 256 KiB
    uint64_t* in_bits  = (uint64_t*)ws;  ws += (size_t)B_ * DW * 8;        // 64 KiB
    _Float16* simf     = (_Float16*)ws;  ws += (size_t)F_ * B_ * V_ * 2;   // 2 MiB
    int*      flags    = (int*)ws;       ws += 32 * 4;
    int*      keys     = (int*)ws;       ws += B_ * F_ * 4;

    k_setup<<<512, 256, 0, stream>>>(cb, inite, inputs, cb_bits, est_bits,
                                     in_bits, flags, keys);
    k_packT<<<dim3(32, 16, 4), 256, 0, stream>>>(cb_bits, cbT_bits);

    for (int i = 0; i < ITERS; ++i) {
        k_sim<<<dim3(32, 4, 4), 256, 0, stream>>>(cb_bits, in_bits, est_bits, simf, flags, i);
        k_gemm<<<dim3(64, 2, 4), 256, 0, stream>>>(simf, cbT_bits, est_bits, flags, i);
    }
    k_argmax<<<dim3(64, 4), 256, 0, stream>>>(cb_bits, est_bits, keys);
    k_final<<<2, 256, 0, stream>>>(keys, flags, out);
}